// Round 2
// baseline (295.094 us; speedup 1.0000x reference)
//
#include <hip/hip_runtime.h>
#include <hip/hip_bf16.h>
#include <math.h>

constexpr int F   = 1433;          // FEAT
constexpr int NB  = 64;            // batch
constexpr int KN  = 8;             // neighbors
constexpr int BF  = NB * F;        // 91712
constexpr int FF  = F * F;         // 2053489
constexpr float EPS = 1e-5f;

// Workspace layout (float offsets), all multiples of 64 floats
constexpr int O_YS = 0;                      // [BF]    ys
constexpr int O_D  = O_YS + BF;              // [BF]    column sums D
constexpr int O_P  = O_D + BF;               // [4*BF]  float4 (x, ys, w=x/D, q=1/D)
constexpr int O_Y1 = O_P + 4 * BF;           // [BF]    y1
constexpr int O_HT = O_Y1 + BF;              // [F*128] Ht[f][m]
constexpr int O_Y2 = O_HT + F * 128;         // [2*BF]  y2[m][f]
constexpr int O_AB = O_Y2 + 2 * BF;          // [FF halfs] bf16 A[f][g]
constexpr int O_ST = O_AB + 1026752;         // [64]    stats
// total ~2.04M floats = 8.1 MB (round-1 used 11.55 MB successfully)

// ---------------- K1: ys[b,g] = sum_k neighbor[b,k,g] ----------------
__global__ __launch_bounds__(256) void k_ys(const float* __restrict__ nb,
                                            float* __restrict__ ys) {
  int i = blockIdx.x * 256 + threadIdx.x;
  if (i >= BF) return;
  int b = i / F, g = i - b * F;
  const float* p = nb + (size_t)b * KN * F + g;
  float s = 0.f;
#pragma unroll
  for (int k = 0; k < KN; ++k) s += p[k * F];
  ys[i] = s;
}

// ---------------- K2: D[b,g] = sum_f sqrt(ys_g*x_f + x_g*ys_f) ----------------
// thread per g; f-loop over LDS broadcast float4 (conflict-free)
__global__ __launch_bounds__(128) void k_D(const float* __restrict__ x,
                                           const float* __restrict__ ys,
                                           float* __restrict__ D) {
  __shared__ __align__(16) float2 xy[1434];
  const int b = blockIdx.x;
  for (int i = threadIdx.x; i < F; i += 128)
    xy[i] = make_float2(x[b * F + i], ys[b * F + i]);
  __syncthreads();
  const int g = blockIdx.y * 128 + threadIdx.x;
  float gx = 0.f, gy = 0.f;
  if (g < F) { gx = xy[g].x; gy = xy[g].y; }
  const float4* xy4 = (const float4*)xy;
  float a0 = 0.f, a1 = 0.f;
#pragma unroll 4
  for (int j = 0; j < 716; ++j) {          // elems 0..1431
    float4 p = xy4[j];
    a0 += __builtin_amdgcn_sqrtf(fmaf(gy, p.x, gx * p.y));
    a1 += __builtin_amdgcn_sqrtf(fmaf(gy, p.z, gx * p.w));
  }
  a0 += __builtin_amdgcn_sqrtf(fmaf(gy, xy[1432].x, gx * xy[1432].y));
  if (g < F) D[b * F + g] = a0 + a1;
}

// ---------------- K2b: pack P = (x, ys, x/D, 1/D) ----------------
__global__ __launch_bounds__(256) void k_pack(const float* __restrict__ x,
                                              const float* __restrict__ ys,
                                              const float* __restrict__ D,
                                              float4* __restrict__ P) {
  int i = blockIdx.x * 256 + threadIdx.x;
  if (i >= BF) return;
  float d = D[i];
  float inv = (d > 0.f) ? 1.f / d : 0.f;
  P[i] = make_float4(x[i], ys[i], x[i] * inv, inv);
}

// ---------------- K3: y1[b,f] = x[b,f] + sum_g sqrt(x_f ys_g + ys_f x_g) * w_g
__global__ __launch_bounds__(128) void k_y1(const float4* __restrict__ P,
                                            float* __restrict__ y1) {
  __shared__ __align__(16) float4 pl[1433];
  const int b = blockIdx.x;
  for (int i = threadIdx.x; i < F; i += 128) pl[i] = P[b * F + i];
  __syncthreads();
  const int f = blockIdx.y * 128 + threadIdx.x;
  float fx = 0.f, fy = 0.f;
  if (f < F) { fx = pl[f].x; fy = pl[f].y; }
  float acc = 0.f;
#pragma unroll 4
  for (int g = 0; g < F; ++g) {
    float4 p = pl[g];
    acc = fmaf(__builtin_amdgcn_sqrtf(fmaf(fx, p.y, fy * p.x)), p.z, acc);
  }
  if (f < F) y1[b * F + f] = fx + acc;
}

// ---------------- K4: A[f,g] = sum_b sqrt(t)*q[b,g]  (bf16 out; adj_buf==0 skipped)
__global__ __launch_bounds__(256) void k_A(const float* __restrict__ x,
                                           const float* __restrict__ ys,
                                           const float4* __restrict__ P,
                                           __hip_bfloat16* __restrict__ Ab) {
  __shared__ float fxl[8][64], fyl[8][64];
  const int fbase = blockIdx.y * 8;
  for (int i = threadIdx.x; i < 512; i += 256) {
    int b = i >> 3, j = i & 7;
    int f = fbase + j;
    float vx = 0.f, vy = 0.f;
    if (f < F) { vx = x[b * F + f]; vy = ys[b * F + f]; }
    fxl[j][b] = vx;
    fyl[j][b] = vy;
  }
  __syncthreads();
  const int g = blockIdx.x * 256 + threadIdx.x;
  if (g >= F) return;
  float acc[8] = {};
  for (int b = 0; b < NB; ++b) {
    float4 p = P[b * F + g];
#pragma unroll
    for (int j = 0; j < 8; ++j) {
      float t = fmaf(fxl[j][b], p.y, p.x * fyl[j][b]);
      acc[j] = fmaf(__builtin_amdgcn_sqrtf(t), p.w, acc[j]);
    }
  }
#pragma unroll
  for (int j = 0; j < 8; ++j) {
    int f = fbase + j;
    if (f < F) Ab[(size_t)f * F + g] = __float2bfloat16(acc[j]);
  }
}

// ---------------- K5: sum / sumsq of y1 ----------------
__global__ __launch_bounds__(256) void k_stats1(const float* __restrict__ y1,
                                                float* __restrict__ stats) {
  float s = 0.f, sq = 0.f;
  for (int i = blockIdx.x * 256 + threadIdx.x; i < BF; i += gridDim.x * 256) {
    float v = y1[i];
    s += v;
    sq += v * v;
  }
#pragma unroll
  for (int o = 32; o; o >>= 1) {
    s += __shfl_down(s, o, 64);
    sq += __shfl_down(sq, o, 64);
  }
  __shared__ float ls[4], lq[4];
  int wave = threadIdx.x >> 6, lane = threadIdx.x & 63;
  if (lane == 0) { ls[wave] = s; lq[wave] = sq; }
  __syncthreads();
  if (threadIdx.x == 0) {
    atomicAdd(&stats[0], ls[0] + ls[1] + ls[2] + ls[3]);
    atomicAdd(&stats[1], lq[0] + lq[1] + lq[2] + lq[3]);
  }
}

// ---------------- K5b: BN1 constants ----------------
__global__ void k_bn1c(const float* __restrict__ W1, const float* __restrict__ g1,
                       const float* __restrict__ be1, float* __restrict__ stats) {
  float mu = stats[0] / (float)BF;
  float var = stats[1] / (float)BF - mu * mu;
  for (int c = 0; c < 2; ++c) {
    float w = W1[c];
    float kc = w * g1[c] / sqrtf(w * w * var + EPS);
    stats[8 + c] = kc;
    stats[10 + c] = -kc * mu + be1[c];
  }
}

// ---------------- K6: Ht[f][m] = softsign(k_c*y1+c_c); y2[m][f] = 64*H ----------------
__global__ __launch_bounds__(256) void k_h1(const float* __restrict__ y1,
                                            const float* __restrict__ stats,
                                            float* __restrict__ Ht,
                                            float* __restrict__ y2) {
  __shared__ float H[16][132];
  const int f0 = blockIdx.x * 16;
  const float k0 = stats[8], k1 = stats[9], c0 = stats[10], c1 = stats[11];
#pragma unroll
  for (int r = 0; r < 4; ++r) {
    int idx = threadIdx.x + r * 256;       // 1024 = 64b x 16f
    int b = idx >> 4, ff = idx & 15;
    int f = f0 + ff;
    float v = (f < F) ? y1[b * F + f] : 0.f;
    float h0 = fmaf(k0, v, c0); h0 = h0 / (1.f + fabsf(h0));
    float h1 = fmaf(k1, v, c1); h1 = h1 / (1.f + fabsf(h1));
    H[ff][2 * b] = h0;
    H[ff][2 * b + 1] = h1;
  }
  __syncthreads();
#pragma unroll
  for (int r = 0; r < 2; ++r) {            // Ht rows: 16 x 128 floats
    int idx = threadIdx.x + r * 256;
    int ff = idx >> 5, c4 = (idx & 31) * 4;
    int f = f0 + ff;
    if (f < F) *(float4*)&Ht[f * 128 + c4] = *(const float4*)&H[ff][c4];
  }
#pragma unroll
  for (int r = 0; r < 8; ++r) {            // y2 init: 128m x 16f
    int idx = threadIdx.x + r * 256;
    int m = idx >> 4, ff = idx & 15;
    int f = f0 + ff;
    if (f < F) y2[m * F + f] = 64.f * H[ff][m];
  }
}

// ---------------- K7: y2[m,f] += sum_g A[f,g]*H[m,g], double-buffered ----------------
constexpr int SPLITS = 16;
constexpr int KCH = 90;                    // ceil(1433/16)
struct Pref { ushort a[4]; float4 h[4]; };

__device__ __forceinline__ void loadRegs(const ushort* __restrict__ Ab,
                                         const float* __restrict__ Ht,
                                         int f0, int ffs, int g4s, int tid,
                                         int gc, Pref& p) {
  int f = min(f0 + ffs, F - 1);
#pragma unroll
  for (int k = 0; k < 4; ++k) {
    int g = min(gc + g4s + k, F - 1);
    p.a[k] = Ab[f * F + g];
  }
#pragma unroll
  for (int r = 0; r < 4; ++r) {
    int idx = tid + 256 * r;
    int gi = idx >> 5, c4 = (idx & 31) << 2;
    int g = min(gc + gi, F - 1);
    p.h[r] = *(const float4*)&Ht[g * 128 + c4];
  }
}

__device__ __forceinline__ void storeLDS(float* __restrict__ Al, float* __restrict__ Hl,
                                         int f0, int ffs, int g4s, int tid,
                                         int gc, int ge, const Pref& p) {
  bool fv = (f0 + ffs) < F;
#pragma unroll
  for (int k = 0; k < 4; ++k) {
    int g = gc + g4s + k;
    float v = 0.f;
    if (fv && g < ge) {
      __hip_bfloat16 bb = *(const __hip_bfloat16*)&p.a[k];
      v = __bfloat162float(bb);
    }
    Al[(g4s + k) * 36 + ffs] = v;
  }
#pragma unroll
  for (int r = 0; r < 4; ++r) {
    int idx = tid + 256 * r;
    int gi = idx >> 5, c4 = (idx & 31) << 2;
    float4 h = p.h[r];
    if (gc + gi >= ge) h = make_float4(0.f, 0.f, 0.f, 0.f);
    *(float4*)&Hl[gi * 132 + c4] = h;
  }
}

__global__ __launch_bounds__(256) void k_gemm(const ushort* __restrict__ Ab,
                                              const float* __restrict__ Ht,
                                              float* __restrict__ y2) {
  __shared__ __align__(16) float Al[2][32 * 36];
  __shared__ __align__(16) float Hl[2][32 * 132];
  const int f0 = blockIdx.x * 32;
  const int gs = blockIdx.y * KCH;
  const int ge = min(gs + KCH, F);
  const int tid = threadIdx.x;
  const int ffs = tid >> 3;                // staging: f row
  const int g4s = (tid & 7) * 4;           // staging: g offset
  const int fsub = (tid & 7) * 4;          // compute: 4 f
  const int msub = (tid >> 3) * 4;         // compute: 4 m
  float acc[4][4] = {};
  const int nch = (ge - gs + 31) >> 5;

  Pref p;
  loadRegs((const ushort*)Ab, Ht, f0, ffs, g4s, tid, gs, p);
  storeLDS(Al[0], Hl[0], f0, ffs, g4s, tid, gs, ge, p);
  __syncthreads();

  for (int c = 0; c < nch; ++c) {
    const int buf = c & 1;
    const bool more = (c + 1 < nch);
    if (more) loadRegs((const ushort*)Ab, Ht, f0, ffs, g4s, tid, gs + (c + 1) * 32, p);
    const float* Ab_ = Al[buf];
    const float* Hb_ = Hl[buf];
#pragma unroll 4
    for (int gi = 0; gi < 32; ++gi) {
      float4 a4 = *(const float4*)&Ab_[gi * 36 + fsub];
      float4 h4 = *(const float4*)&Hb_[gi * 132 + msub];
      float av[4] = {a4.x, a4.y, a4.z, a4.w};
      float hv[4] = {h4.x, h4.y, h4.z, h4.w};
#pragma unroll
      for (int i = 0; i < 4; ++i)
#pragma unroll
        for (int j = 0; j < 4; ++j)
          acc[i][j] = fmaf(av[i], hv[j], acc[i][j]);
    }
    if (more) storeLDS(Al[buf ^ 1], Hl[buf ^ 1], f0, ffs, g4s, tid, gs + (c + 1) * 32, ge, p);
    __syncthreads();
  }

#pragma unroll
  for (int i = 0; i < 4; ++i) {
    int f = f0 + fsub + i;
    if (f < F) {
#pragma unroll
      for (int j = 0; j < 4; ++j)
        atomicAdd(&y2[(msub + j) * F + f], acc[i][j]);
    }
  }
}

// ---------------- K8: 5 moments of (u,v) ----------------
__global__ __launch_bounds__(256) void k_stats2(const float* __restrict__ y2,
                                                float* __restrict__ stats) {
  float su = 0.f, sv = 0.f, suu = 0.f, svv = 0.f, suv = 0.f;
  for (int i = blockIdx.x * 256 + threadIdx.x; i < BF; i += gridDim.x * 256) {
    int b = i / F, f = i - b * F;
    float u = y2[(2 * b) * F + f];
    float v = y2[(2 * b + 1) * F + f];
    su += u; sv += v; suu += u * u; svv += v * v; suv += u * v;
  }
#pragma unroll
  for (int o = 32; o; o >>= 1) {
    su += __shfl_down(su, o, 64);
    sv += __shfl_down(sv, o, 64);
    suu += __shfl_down(suu, o, 64);
    svv += __shfl_down(svv, o, 64);
    suv += __shfl_down(suv, o, 64);
  }
  __shared__ float red[5][4];
  int wave = threadIdx.x >> 6, lane = threadIdx.x & 63;
  if (lane == 0) {
    red[0][wave] = su; red[1][wave] = sv; red[2][wave] = suu;
    red[3][wave] = svv; red[4][wave] = suv;
  }
  __syncthreads();
  if (threadIdx.x == 0) {
    atomicAdd(&stats[2], red[0][0] + red[0][1] + red[0][2] + red[0][3]);
    atomicAdd(&stats[3], red[1][0] + red[1][1] + red[1][2] + red[1][3]);
    atomicAdd(&stats[4], red[2][0] + red[2][1] + red[2][2] + red[2][3]);
    atomicAdd(&stats[5], red[3][0] + red[3][1] + red[3][2] + red[3][3]);
    atomicAdd(&stats[6], red[4][0] + red[4][1] + red[4][2] + red[4][3]);
  }
}

// ---------------- K8b: BN2 constants ----------------
__global__ void k_bn2c(const float* __restrict__ W2, const float* __restrict__ b2,
                       const float* __restrict__ g2, const float* __restrict__ be2,
                       float* __restrict__ stats) {
  float n = (float)BF;
  float Eu = stats[2] / n, Ev = stats[3] / n;
  float Euu = stats[4] / n, Evv = stats[5] / n, Euv = stats[6] / n;
  for (int o = 0; o < 2; ++o) {
    float w0 = W2[o * 2 + 0], w1 = W2[o * 2 + 1];
    float mean = w0 * Eu + w1 * Ev + b2[o];
    float Eh2 = w0 * w0 * Euu + 2.f * w0 * w1 * Euv + w1 * w1 * Evv +
                2.f * b2[o] * (w0 * Eu + w1 * Ev) + b2[o] * b2[o];
    float var = Eh2 - mean * mean;
    float inv = g2[o] / sqrtf(var + EPS);
    stats[16 + o * 3 + 0] = w0 * inv;
    stats[16 + o * 3 + 1] = w1 * inv;
    stats[16 + o * 3 + 2] = (b2[o] - mean) * inv + be2[o];
  }
}

// ---------------- K9: final classifier ----------------
__global__ __launch_bounds__(256) void k_out(const float* __restrict__ y2,
                                             const float* __restrict__ stats,
                                             const float* __restrict__ Wc,
                                             const float* __restrict__ bc,
                                             float* __restrict__ out) {
  const int b = blockIdx.x;
  float A0 = stats[16], B0 = stats[17], C0 = stats[18];
  float A1 = stats[19], B1 = stats[20], C1 = stats[21];
  float acc[7] = {};
  for (int f = threadIdx.x; f < F; f += 256) {
    float u = y2[(2 * b) * F + f], v = y2[(2 * b + 1) * F + f];
    float h0 = fmaf(A0, u, fmaf(B0, v, C0));
    h0 = h0 / (1.f + fabsf(h0));
    float h1 = fmaf(A1, u, fmaf(B1, v, C1));
    h1 = h1 / (1.f + fabsf(h1));
#pragma unroll
    for (int o = 0; o < 7; ++o) acc[o] = fmaf(Wc[o * (2 * F) + f], h0, acc[o]);
#pragma unroll
    for (int o = 0; o < 7; ++o) acc[o] = fmaf(Wc[o * (2 * F) + F + f], h1, acc[o]);
  }
#pragma unroll
  for (int o = 0; o < 7; ++o) {
#pragma unroll
    for (int s = 32; s; s >>= 1) acc[o] += __shfl_down(acc[o], s, 64);
  }
  __shared__ float red[7][4];
  int wave = threadIdx.x >> 6, lane = threadIdx.x & 63;
  if (lane == 0) {
#pragma unroll
    for (int o = 0; o < 7; ++o) red[o][wave] = acc[o];
  }
  __syncthreads();
  if (threadIdx.x < 7) {
    int o = threadIdx.x;
    out[b * 7 + o] = red[o][0] + red[o][1] + red[o][2] + red[o][3] + bc[o];
  }
}

extern "C" void kernel_launch(void* const* d_in, const int* in_sizes, int n_in,
                              void* d_out, int out_size, void* d_ws, size_t ws_size,
                              hipStream_t stream) {
  const float* x    = (const float*)d_in[0];
  const float* nb   = (const float*)d_in[1];
  const float* W1   = (const float*)d_in[3];
  const float* W2   = (const float*)d_in[5];
  const float* b2   = (const float*)d_in[6];
  const float* g1   = (const float*)d_in[7];
  const float* be1  = (const float*)d_in[8];
  const float* g2   = (const float*)d_in[9];
  const float* be2  = (const float*)d_in[10];
  const float* Wc   = (const float*)d_in[11];
  const float* bc   = (const float*)d_in[12];
  float* out = (float*)d_out;
  float* ws = (float*)d_ws;

  float*  ys = ws + O_YS;
  float*  D  = ws + O_D;
  float4* P  = (float4*)(ws + O_P);
  float*  y1 = ws + O_Y1;
  float*  Ht = ws + O_HT;
  float*  y2 = ws + O_Y2;
  __hip_bfloat16* Ab = (__hip_bfloat16*)(ws + O_AB);
  float*  st = ws + O_ST;

  hipMemsetAsync(st, 0, 32 * sizeof(float), stream);

  k_ys    <<<(BF + 255) / 256, 256, 0, stream>>>(nb, ys);
  k_D     <<<dim3(NB, 12), 128, 0, stream>>>(x, ys, D);
  k_pack  <<<(BF + 255) / 256, 256, 0, stream>>>(x, ys, D, P);
  k_y1    <<<dim3(NB, 12), 128, 0, stream>>>(P, y1);
  k_A     <<<dim3((F + 255) / 256, (F + 7) / 8), 256, 0, stream>>>(x, ys, P, Ab);
  k_stats1<<<128, 256, 0, stream>>>(y1, st);
  k_bn1c  <<<1, 1, 0, stream>>>(W1, g1, be1, st);
  k_h1    <<<(F + 15) / 16, 256, 0, stream>>>(y1, st, Ht, y2);
  k_gemm  <<<dim3((F + 31) / 32, SPLITS), 256, 0, stream>>>((const ushort*)Ab, Ht, y2);
  k_stats2<<<128, 256, 0, stream>>>(y2, st);
  k_bn2c  <<<1, 1, 0, stream>>>(W2, b2, g2, be2, st);
  k_out   <<<NB, 256, 0, stream>>>(y2, st, Wc, bc, out);
}

// Round 3
// 219.783 us; speedup vs baseline: 1.3427x; 1.3427x over previous
//
#include <hip/hip_runtime.h>
#include <hip/hip_bf16.h>
#include <math.h>

constexpr int F   = 1433;
constexpr int NB  = 64;
constexpr int KN  = 8;
constexpr int BF  = NB * F;            // 91712
constexpr float EPS = 1e-5f;

constexpr int SF  = 8;                 // splits for k_D / k_y1
constexpr int CH  = (F + SF - 1) / SF; // 180
constexpr int SK  = 4;                 // gemm K-splits
constexpr int KCH = (F + SK - 1) / SK; // 359
constexpr int FT  = 16;                // k_A f-tile

// Workspace layout (float offsets). BIG is reused 3x:
//   k_D partials [SF][BF] -> k_y1 partials [SF][BF] -> gemm partials [SK][128*F]
constexpr int O_YS  = 0;                    // [BF]
constexpr int O_BIG = O_YS + BF;            // [8*BF] = 733696
constexpr int O_P   = O_BIG + 8 * BF;       // [4*BF] float4 (x, ys, x/D, 1/D)
constexpr int O_Y1  = O_P + 4 * BF;         // [BF]
constexpr int O_HT  = O_Y1 + BF;            // [F*128] Ht[f][m]
constexpr int O_Y2  = O_HT + 128 * F;       // [2*BF]  y2[m][f]
constexpr int O_AB  = O_Y2 + 2 * BF;        // [1026752 floats] bf16 A[f][g]
constexpr int O_ST  = O_AB + 1026752;       // [64] stats
// total = 2,677,632 floats = 10.71 MB (< 11.55 MB proven in round 1)

// ---------------- K1: ys[b,g] = sum_k neighbor[b,k,g] ----------------
__global__ __launch_bounds__(256) void k_ys(const float* __restrict__ nb,
                                            float* __restrict__ ys) {
  int i = blockIdx.x * 256 + threadIdx.x;
  if (i >= BF) return;
  int b = i / F, g = i - b * F;
  const float* p = nb + (size_t)b * KN * F + g;
  float s = 0.f;
#pragma unroll
  for (int k = 0; k < KN; ++k) s += p[k * F];
  ys[i] = s;
}

// ---------------- K2: D partials over f-chunks ----------------
// DP[s][b*F+g] = sum_{f in chunk s} sqrt(ys_g*x_f + x_g*ys_f)
__global__ __launch_bounds__(256) void k_D(const float* __restrict__ x,
                                           const float* __restrict__ ys,
                                           float* __restrict__ DP) {
  __shared__ __align__(16) float2 xy[CH];
  const int b = blockIdx.x, s = blockIdx.y;
  const int cs = s * CH, ce = min(cs + CH, F), cn = ce - cs;
  for (int i = threadIdx.x; i < cn; i += 256)
    xy[i] = make_float2(x[b * F + cs + i], ys[b * F + cs + i]);
  __syncthreads();
  float gx[6], gy[6], acc[6] = {};
#pragma unroll
  for (int j = 0; j < 6; ++j) {
    int g = threadIdx.x + 256 * j;
    gx[j] = (g < F) ? x[b * F + g] : 0.f;
    gy[j] = (g < F) ? ys[b * F + g] : 0.f;
  }
  for (int i = 0; i < cn; ++i) {
    float2 p = xy[i];   // broadcast read, conflict-free
#pragma unroll
    for (int j = 0; j < 6; ++j)
      acc[j] += __builtin_amdgcn_sqrtf(fmaf(gy[j], p.x, gx[j] * p.y));
  }
#pragma unroll
  for (int j = 0; j < 6; ++j) {
    int g = threadIdx.x + 256 * j;
    if (g < F) DP[(size_t)s * BF + b * F + g] = acc[j];
  }
}

// ---------------- K2b: reduce D partials, pack P = (x, ys, x/D, 1/D) ------
__global__ __launch_bounds__(256) void k_pack(const float* __restrict__ x,
                                              const float* __restrict__ ys,
                                              const float* __restrict__ DP,
                                              float4* __restrict__ P) {
  int i = blockIdx.x * 256 + threadIdx.x;
  if (i >= BF) return;
  float d = 0.f;
#pragma unroll
  for (int s = 0; s < SF; ++s) d += DP[(size_t)s * BF + i];
  float inv = (d > 0.f) ? 1.f / d : 0.f;
  P[i] = make_float4(x[i], ys[i], x[i] * inv, inv);
}

// ---------------- K3: y1 partials over g-chunks ----------------
// Y1P[s][b*F+f] = sum_{g in chunk} sqrt(x_f*ys_g + ys_f*x_g) * w_g
__global__ __launch_bounds__(256) void k_y1(const float4* __restrict__ P,
                                            float* __restrict__ Y1P) {
  __shared__ __align__(16) float4 pl[CH];
  const int b = blockIdx.x, s = blockIdx.y;
  const int cs = s * CH, ce = min(cs + CH, F), cn = ce - cs;
  for (int i = threadIdx.x; i < cn; i += 256) pl[i] = P[b * F + cs + i];
  __syncthreads();
  float fx[6], fy[6], acc[6] = {};
#pragma unroll
  for (int j = 0; j < 6; ++j) {
    int f = threadIdx.x + 256 * j;
    float4 p = (f < F) ? P[b * F + f] : make_float4(0.f, 0.f, 0.f, 0.f);
    fx[j] = p.x; fy[j] = p.y;
  }
  for (int i = 0; i < cn; ++i) {
    float4 p = pl[i];   // broadcast
#pragma unroll
    for (int j = 0; j < 6; ++j)
      acc[j] = fmaf(__builtin_amdgcn_sqrtf(fmaf(fx[j], p.y, fy[j] * p.x)), p.z, acc[j]);
  }
#pragma unroll
  for (int j = 0; j < 6; ++j) {
    int f = threadIdx.x + 256 * j;
    if (f < F) Y1P[(size_t)s * BF + b * F + f] = acc[j];
  }
}

// ---------------- K4: A[f,g] = sum_b sqrt(t)*q[b,g] -> bf16 ----------------
__global__ __launch_bounds__(256) void k_A(const float* __restrict__ x,
                                           const float* __restrict__ ys,
                                           const float4* __restrict__ P,
                                           __hip_bfloat16* __restrict__ Ab) {
  __shared__ float2 fxy[FT][NB];   // 8 KB
  const int fbase = blockIdx.y * FT;
  for (int i = threadIdx.x; i < FT * NB; i += 256) {
    int b = i >> 4, j = i & 15;
    int f = fbase + j;
    float vx = 0.f, vy = 0.f;
    if (f < F) { vx = x[b * F + f]; vy = ys[b * F + f]; }
    fxy[j][b] = make_float2(vx, vy);
  }
  __syncthreads();
  const int g = blockIdx.x * 256 + threadIdx.x;
  if (g >= F) return;
  float acc[FT] = {};
  for (int b = 0; b < NB; ++b) {
    float4 p = P[b * F + g];
#pragma unroll
    for (int j = 0; j < FT; ++j) {
      float2 w = fxy[j][b];   // broadcast
      acc[j] = fmaf(__builtin_amdgcn_sqrtf(fmaf(w.x, p.y, p.x * w.y)), p.w, acc[j]);
    }
  }
#pragma unroll
  for (int j = 0; j < FT; ++j) {
    int f = fbase + j;
    if (f < F) Ab[(size_t)f * F + g] = __float2bfloat16(acc[j]);
  }
}

// ---------------- K5: reduce y1 partials (+x term), sum/sumsq ----------------
__global__ __launch_bounds__(256) void k_stats1(const float4* __restrict__ P,
                                                const float* __restrict__ Y1P,
                                                float* __restrict__ y1,
                                                float* __restrict__ st) {
  float s = 0.f, sq = 0.f;
  for (int i = blockIdx.x * 256 + threadIdx.x; i < BF; i += gridDim.x * 256) {
    float v = P[i].x;
#pragma unroll
    for (int k = 0; k < SF; ++k) v += Y1P[(size_t)k * BF + i];
    y1[i] = v;
    s += v; sq += v * v;
  }
#pragma unroll
  for (int o = 32; o; o >>= 1) {
    s += __shfl_down(s, o, 64);
    sq += __shfl_down(sq, o, 64);
  }
  __shared__ float ls[4], lq[4];
  int wave = threadIdx.x >> 6, lane = threadIdx.x & 63;
  if (lane == 0) { ls[wave] = s; lq[wave] = sq; }
  __syncthreads();
  if (threadIdx.x == 0) {
    atomicAdd(&st[0], ls[0] + ls[1] + ls[2] + ls[3]);
    atomicAdd(&st[1], lq[0] + lq[1] + lq[2] + lq[3]);
  }
}

// ---------------- K6: h1 = softsign(k_c*y1+c_c) -> Ht[f][m], y2 init = 64*H ----
__global__ __launch_bounds__(256) void k_h1(const float* __restrict__ y1,
                                            const float* __restrict__ st,
                                            const float* __restrict__ W1,
                                            const float* __restrict__ g1,
                                            const float* __restrict__ be1,
                                            float* __restrict__ Ht,
                                            float* __restrict__ y2) {
  // BN1 constants (b1 cancels inside BN)
  float mu = st[0] / (float)BF;
  float var = st[1] / (float)BF - mu * mu;
  float wa = W1[0], wb = W1[1];
  float k0 = wa * g1[0] / sqrtf(wa * wa * var + EPS);
  float k1 = wb * g1[1] / sqrtf(wb * wb * var + EPS);
  float c0 = -k0 * mu + be1[0];
  float c1 = -k1 * mu + be1[1];

  __shared__ float H[16][132];
  const int f0 = blockIdx.x * 16;
#pragma unroll
  for (int r = 0; r < 4; ++r) {
    int idx = threadIdx.x + r * 256;   // 1024 = 64b x 16f
    int b = idx >> 4, ff = idx & 15;
    int f = f0 + ff;
    float v = (f < F) ? y1[b * F + f] : 0.f;
    float h0 = fmaf(k0, v, c0); h0 = h0 / (1.f + fabsf(h0));
    float h1 = fmaf(k1, v, c1); h1 = h1 / (1.f + fabsf(h1));
    H[ff][2 * b] = h0;
    H[ff][2 * b + 1] = h1;
  }
  __syncthreads();
#pragma unroll
  for (int r = 0; r < 2; ++r) {        // Ht rows: 16 x 128
    int idx = threadIdx.x + r * 256;
    int ff = idx >> 5, c4 = (idx & 31) * 4;
    int f = f0 + ff;
    if (f < F) *(float4*)&Ht[f * 128 + c4] = *(const float4*)&H[ff][c4];
  }
#pragma unroll
  for (int r = 0; r < 8; ++r) {        // y2 init: 128m x 16f
    int idx = threadIdx.x + r * 256;
    int m = idx >> 4, ff = idx & 15;
    int f = f0 + ff;
    if (f < F) y2[m * F + f] = 64.f * H[ff][m];
  }
}

// ---------------- K7: gemm partials G2P[s][m][f] = sum_{g in split} A[f,g]*H[m,g]
struct Pref { ushort a[4]; float4 h[4]; };

__device__ __forceinline__ void loadRegs(const ushort* __restrict__ Ab,
                                         const float* __restrict__ Ht,
                                         int f0, int ffs, int g4s, int tid,
                                         int gc, Pref& p) {
  int f = min(f0 + ffs, F - 1);
#pragma unroll
  for (int k = 0; k < 4; ++k) {
    int g = min(gc + g4s + k, F - 1);
    p.a[k] = Ab[(size_t)f * F + g];
  }
#pragma unroll
  for (int r = 0; r < 4; ++r) {
    int idx = tid + 256 * r;
    int gi = idx >> 5, c4 = (idx & 31) << 2;
    int g = min(gc + gi, F - 1);
    p.h[r] = *(const float4*)&Ht[g * 128 + c4];
  }
}

__device__ __forceinline__ void storeLDS(float* __restrict__ Al, float* __restrict__ Hl,
                                         int f0, int ffs, int g4s, int tid,
                                         int gc, int ge, const Pref& p) {
  bool fv = (f0 + ffs) < F;
#pragma unroll
  for (int k = 0; k < 4; ++k) {
    int g = gc + g4s + k;
    float v = 0.f;
    if (fv && g < ge) {
      __hip_bfloat16 bb = *(const __hip_bfloat16*)&p.a[k];
      v = __bfloat162float(bb);
    }
    Al[(g4s + k) * 36 + ffs] = v;
  }
#pragma unroll
  for (int r = 0; r < 4; ++r) {
    int idx = tid + 256 * r;
    int gi = idx >> 5, c4 = (idx & 31) << 2;
    float4 h = p.h[r];
    if (gc + gi >= ge) h = make_float4(0.f, 0.f, 0.f, 0.f);
    *(float4*)&Hl[gi * 132 + c4] = h;
  }
}

__global__ __launch_bounds__(256) void k_gemm(const ushort* __restrict__ Ab,
                                              const float* __restrict__ Ht,
                                              float* __restrict__ G2P) {
  __shared__ __align__(16) float Al[2][32 * 36];
  __shared__ __align__(16) float Hl[2][32 * 132];
  const int f0 = blockIdx.x * 32;
  const int gs = blockIdx.y * KCH;
  const int ge = min(gs + KCH, F);
  const int tid = threadIdx.x;
  const int ffs = tid >> 3;
  const int g4s = (tid & 7) * 4;
  const int fsub = (tid & 7) * 4;
  const int msub = (tid >> 3) * 4;
  float acc[4][4] = {};
  const int nch = (ge - gs + 31) >> 5;

  Pref p;
  loadRegs(Ab, Ht, f0, ffs, g4s, tid, gs, p);
  storeLDS(Al[0], Hl[0], f0, ffs, g4s, tid, gs, ge, p);
  __syncthreads();

  for (int c = 0; c < nch; ++c) {
    const int buf = c & 1;
    const bool more = (c + 1 < nch);
    if (more) loadRegs(Ab, Ht, f0, ffs, g4s, tid, gs + (c + 1) * 32, p);
    const float* Ab_ = Al[buf];
    const float* Hb_ = Hl[buf];
#pragma unroll 4
    for (int gi = 0; gi < 32; ++gi) {
      float4 a4 = *(const float4*)&Ab_[gi * 36 + fsub];
      float4 h4 = *(const float4*)&Hb_[gi * 132 + msub];
      float av[4] = {a4.x, a4.y, a4.z, a4.w};
      float hv[4] = {h4.x, h4.y, h4.z, h4.w};
#pragma unroll
      for (int i = 0; i < 4; ++i)
#pragma unroll
        for (int j = 0; j < 4; ++j)
          acc[i][j] = fmaf(av[i], hv[j], acc[i][j]);
    }
    if (more) storeLDS(Al[buf ^ 1], Hl[buf ^ 1], f0, ffs, g4s, tid, gs + (c + 1) * 32, ge, p);
    __syncthreads();
  }

  float* dst = G2P + (size_t)blockIdx.y * 128 * F;
#pragma unroll
  for (int i = 0; i < 4; ++i) {
    int f = f0 + fsub + i;
    if (f < F) {
#pragma unroll
      for (int j = 0; j < 4; ++j)
        dst[(msub + j) * F + f] = acc[i][j];
    }
  }
}

// ---------------- K8: reduce gemm partials into y2 + 5 moments ----------------
__global__ __launch_bounds__(256) void k_stats2(float* __restrict__ y2,
                                                const float* __restrict__ G2P,
                                                float* __restrict__ st) {
  float su = 0.f, sv = 0.f, suu = 0.f, svv = 0.f, suv = 0.f;
  for (int i = blockIdx.x * 256 + threadIdx.x; i < BF; i += gridDim.x * 256) {
    int b = i / F, f = i - b * F;
    int iu = (2 * b) * F + f, iv = iu + F;
    float u = y2[iu], v = y2[iv];
#pragma unroll
    for (int s = 0; s < SK; ++s) {
      u += G2P[(size_t)s * 128 * F + iu];
      v += G2P[(size_t)s * 128 * F + iv];
    }
    y2[iu] = u; y2[iv] = v;
    su += u; sv += v; suu += u * u; svv += v * v; suv += u * v;
  }
#pragma unroll
  for (int o = 32; o; o >>= 1) {
    su += __shfl_down(su, o, 64);
    sv += __shfl_down(sv, o, 64);
    suu += __shfl_down(suu, o, 64);
    svv += __shfl_down(svv, o, 64);
    suv += __shfl_down(suv, o, 64);
  }
  __shared__ float red[5][4];
  int wave = threadIdx.x >> 6, lane = threadIdx.x & 63;
  if (lane == 0) {
    red[0][wave] = su; red[1][wave] = sv; red[2][wave] = suu;
    red[3][wave] = svv; red[4][wave] = suv;
  }
  __syncthreads();
  if (threadIdx.x == 0) {
    atomicAdd(&st[2], red[0][0] + red[0][1] + red[0][2] + red[0][3]);
    atomicAdd(&st[3], red[1][0] + red[1][1] + red[1][2] + red[1][3]);
    atomicAdd(&st[4], red[2][0] + red[2][1] + red[2][2] + red[2][3]);
    atomicAdd(&st[5], red[3][0] + red[3][1] + red[3][2] + red[3][3]);
    atomicAdd(&st[6], red[4][0] + red[4][1] + red[4][2] + red[4][3]);
  }
}

// ---------------- K9: final classifier (BN2 consts inline) ----------------
__global__ __launch_bounds__(256) void k_out(const float* __restrict__ y2,
                                             const float* __restrict__ st,
                                             const float* __restrict__ W2,
                                             const float* __restrict__ b2,
                                             const float* __restrict__ g2,
                                             const float* __restrict__ be2,
                                             const float* __restrict__ Wc,
                                             const float* __restrict__ bc,
                                             float* __restrict__ out) {
  float n = (float)BF;
  float Eu = st[2] / n, Ev = st[3] / n;
  float Euu = st[4] / n, Evv = st[5] / n, Euv = st[6] / n;
  float cA[2], cB[2], cC[2];
#pragma unroll
  for (int o = 0; o < 2; ++o) {
    float w0 = W2[o * 2 + 0], w1 = W2[o * 2 + 1];
    float mean = w0 * Eu + w1 * Ev + b2[o];
    float Eh2 = w0 * w0 * Euu + 2.f * w0 * w1 * Euv + w1 * w1 * Evv +
                2.f * b2[o] * (w0 * Eu + w1 * Ev) + b2[o] * b2[o];
    float var = Eh2 - mean * mean;
    float inv = g2[o] / sqrtf(var + EPS);
    cA[o] = w0 * inv;
    cB[o] = w1 * inv;
    cC[o] = (b2[o] - mean) * inv + be2[o];
  }
  const int b = blockIdx.x;
  float acc[7] = {};
  for (int f = threadIdx.x; f < F; f += 256) {
    float u = y2[(2 * b) * F + f], v = y2[(2 * b + 1) * F + f];
    float h0 = fmaf(cA[0], u, fmaf(cB[0], v, cC[0]));
    h0 = h0 / (1.f + fabsf(h0));
    float h1 = fmaf(cA[1], u, fmaf(cB[1], v, cC[1]));
    h1 = h1 / (1.f + fabsf(h1));
#pragma unroll
    for (int o = 0; o < 7; ++o) acc[o] = fmaf(Wc[o * (2 * F) + f], h0, acc[o]);
#pragma unroll
    for (int o = 0; o < 7; ++o) acc[o] = fmaf(Wc[o * (2 * F) + F + f], h1, acc[o]);
  }
#pragma unroll
  for (int o = 0; o < 7; ++o) {
#pragma unroll
    for (int s = 32; s; s >>= 1) acc[o] += __shfl_down(acc[o], s, 64);
  }
  __shared__ float red[7][4];
  int wave = threadIdx.x >> 6, lane = threadIdx.x & 63;
  if (lane == 0) {
#pragma unroll
    for (int o = 0; o < 7; ++o) red[o][wave] = acc[o];
  }
  __syncthreads();
  if (threadIdx.x < 7) {
    int o = threadIdx.x;
    out[b * 7 + o] = red[o][0] + red[o][1] + red[o][2] + red[o][3] + bc[o];
  }
}

extern "C" void kernel_launch(void* const* d_in, const int* in_sizes, int n_in,
                              void* d_out, int out_size, void* d_ws, size_t ws_size,
                              hipStream_t stream) {
  const float* x    = (const float*)d_in[0];
  const float* nb   = (const float*)d_in[1];
  const float* W1   = (const float*)d_in[3];
  const float* W2   = (const float*)d_in[5];
  const float* b2   = (const float*)d_in[6];
  const float* g1   = (const float*)d_in[7];
  const float* be1  = (const float*)d_in[8];
  const float* g2   = (const float*)d_in[9];
  const float* be2  = (const float*)d_in[10];
  const float* Wc   = (const float*)d_in[11];
  const float* bc   = (const float*)d_in[12];
  float* out = (float*)d_out;
  float* ws = (float*)d_ws;

  float*  ys  = ws + O_YS;
  float*  BIG = ws + O_BIG;   // DP -> Y1P -> G2P
  float4* P   = (float4*)(ws + O_P);
  float*  y1  = ws + O_Y1;
  float*  Ht  = ws + O_HT;
  float*  y2  = ws + O_Y2;
  __hip_bfloat16* Ab = (__hip_bfloat16*)(ws + O_AB);
  float*  st  = ws + O_ST;

  hipMemsetAsync(st, 0, 64 * sizeof(float), stream);

  k_ys    <<<(BF + 255) / 256, 256, 0, stream>>>(nb, ys);
  k_D     <<<dim3(NB, SF), 256, 0, stream>>>(x, ys, BIG);
  k_pack  <<<(BF + 255) / 256, 256, 0, stream>>>(x, ys, BIG, P);
  k_y1    <<<dim3(NB, SF), 256, 0, stream>>>(P, BIG);
  k_A     <<<dim3(6, (F + FT - 1) / FT), 256, 0, stream>>>(x, ys, P, Ab);
  k_stats1<<<128, 256, 0, stream>>>(P, BIG, y1, st);
  k_h1    <<<(F + 15) / 16, 256, 0, stream>>>(y1, st, W1, g1, be1, Ht, y2);
  k_gemm  <<<dim3((F + 31) / 32, SK), 256, 0, stream>>>((const ushort*)Ab, Ht, BIG);
  k_stats2<<<128, 256, 0, stream>>>(y2, BIG, st);
  k_out   <<<NB, 256, 0, stream>>>(y2, st, W2, b2, g2, be2, Wc, bc, out);
}

// Round 4
// 213.458 us; speedup vs baseline: 1.3824x; 1.0296x over previous
//
#include <hip/hip_runtime.h>
#include <hip/hip_bf16.h>
#include <math.h>

constexpr int F   = 1433;
constexpr int NB  = 64;
constexpr int KN  = 8;
constexpr int BF  = NB * F;            // 91712
constexpr float EPS = 1e-5f;

constexpr int SF  = 16;                // splits for k_D / k_y1
constexpr int CH  = (F + SF - 1) / SF; // 90
constexpr int SK  = 8;                 // gemm K-splits
constexpr int KCH = (F + SK - 1) / SK; // 180
constexpr int FT  = 16;                // k_A f-tile

// Workspace layout (float offsets). ws is 256 MiB, so no frugality needed.
constexpr int O_YS  = 0;                     // [BF]
constexpr int O_Q   = O_YS + BF;             // [BF]    q = 1/D
constexpr int O_DP  = O_Q + BF;              // [SF*BF] D partials; reused as gemm partials [SK][128*F]
constexpr int O_Y1P = O_DP + SF * BF;        // [SF*BF] y1 partials
constexpr int O_Y1  = O_Y1P + SF * BF;       // [BF]
constexpr int O_HT  = O_Y1 + BF;             // [F*128] Ht[f][m]
constexpr int O_Y2  = O_HT + 128 * F;        // [2*BF]  y2[m][f]
constexpr int O_AB  = O_Y2 + 2 * BF;         // [1026752 floats] bf16 A[f][g]
constexpr int O_ST  = O_AB + 1026752;        // [64] stats
// total ~4.6M floats = 18.4 MB << 256 MiB

// ---------------- K1: D partials; ys computed in-block from neighbor ----------
// DP[s][b*F+g] = sum_{f in chunk s} sqrt(ys_g*x_f + x_g*ys_f)
__global__ __launch_bounds__(256) void k_D(const float* __restrict__ x,
                                           const float* __restrict__ nbr,
                                           float* __restrict__ DP,
                                           float* __restrict__ ys_out) {
  __shared__ __align__(16) float2 xy[F];   // (x, ys) full row: 11.5 KB
  const int b = blockIdx.x, s = blockIdx.y;
  for (int i = threadIdx.x; i < F; i += 256) {
    const float* p = nbr + (size_t)b * KN * F + i;
    float acc = 0.f;
#pragma unroll
    for (int k = 0; k < KN; ++k) acc += p[k * F];
    xy[i] = make_float2(x[b * F + i], acc);
  }
  __syncthreads();
  if (s == 0) {
    for (int i = threadIdx.x; i < F; i += 256) ys_out[b * F + i] = xy[i].y;
  }
  const int cs = s * CH, cn = min(CH, F - cs);
  float gx[6], gy[6], acc[6] = {};
#pragma unroll
  for (int j = 0; j < 6; ++j) {
    int g = threadIdx.x + 256 * j;
    float2 p = (g < F) ? xy[g] : make_float2(0.f, 0.f);
    gx[j] = p.x; gy[j] = p.y;
  }
  for (int i = 0; i < cn; ++i) {
    float2 p = xy[cs + i];   // broadcast read, conflict-free
#pragma unroll
    for (int j = 0; j < 6; ++j)
      acc[j] += __builtin_amdgcn_sqrtf(fmaf(gy[j], p.x, gx[j] * p.y));
  }
#pragma unroll
  for (int j = 0; j < 6; ++j) {
    int g = threadIdx.x + 256 * j;
    if (g < F) DP[(size_t)s * BF + b * F + g] = acc[j];
  }
}

// ---------------- K2: y1 partials; fused D-reduce -> w, q ----------------
// Y1P[s][b*F+f] = sum_{g in chunk s} sqrt(x_f*ys_g + ys_f*x_g) * w_g
__global__ __launch_bounds__(256) void k_y1(const float* __restrict__ x,
                                            const float* __restrict__ ys,
                                            const float* __restrict__ DP,
                                            float* __restrict__ Y1P,
                                            float* __restrict__ q) {
  __shared__ __align__(16) float4 pl[CH];  // (x, ys, w, q) for the g-chunk
  const int b = blockIdx.x, s = blockIdx.y;
  const int cs = s * CH, cn = min(CH, F - cs);
  for (int i = threadIdx.x; i < cn; i += 256) {
    int g = cs + i;
    float d = 0.f;
#pragma unroll
    for (int t = 0; t < SF; ++t) d += DP[(size_t)t * BF + b * F + g];
    float inv = (d > 0.f) ? 1.f / d : 0.f;
    float xv = x[b * F + g], yv = ys[b * F + g];
    pl[i] = make_float4(xv, yv, xv * inv, inv);
    q[b * F + g] = inv;
  }
  __syncthreads();
  float fx[6], fy[6], acc[6] = {};
#pragma unroll
  for (int j = 0; j < 6; ++j) {
    int f = threadIdx.x + 256 * j;
    fx[j] = (f < F) ? x[b * F + f] : 0.f;
    fy[j] = (f < F) ? ys[b * F + f] : 0.f;
  }
  for (int i = 0; i < cn; ++i) {
    float4 p = pl[i];   // broadcast
#pragma unroll
    for (int j = 0; j < 6; ++j)
      acc[j] = fmaf(__builtin_amdgcn_sqrtf(fmaf(fx[j], p.y, fy[j] * p.x)), p.z, acc[j]);
  }
#pragma unroll
  for (int j = 0; j < 6; ++j) {
    int f = threadIdx.x + 256 * j;
    if (f < F) Y1P[(size_t)s * BF + b * F + f] = acc[j];
  }
}

// ---------------- K3: A[f,g] = sum_b sqrt(t)*q[b,g] -> bf16 ----------------
__global__ __launch_bounds__(256) void k_A(const float* __restrict__ x,
                                           const float* __restrict__ ys,
                                           const float* __restrict__ q,
                                           __hip_bfloat16* __restrict__ Ab) {
  __shared__ float2 fxy[FT][NB];   // 8 KB
  const int fbase = blockIdx.y * FT;
  for (int i = threadIdx.x; i < FT * NB; i += 256) {
    int b = i >> 4, j = i & 15;
    int f = fbase + j;
    float vx = 0.f, vy = 0.f;
    if (f < F) { vx = x[b * F + f]; vy = ys[b * F + f]; }
    fxy[j][b] = make_float2(vx, vy);
  }
  __syncthreads();
  const int g = blockIdx.x * 256 + threadIdx.x;
  if (g >= F) return;
  float acc[FT] = {};
  for (int b = 0; b < NB; ++b) {
    float gx = x[b * F + g], gy = ys[b * F + g], gq = q[b * F + g];
#pragma unroll
    for (int j = 0; j < FT; ++j) {
      float2 w = fxy[j][b];   // broadcast
      acc[j] = fmaf(__builtin_amdgcn_sqrtf(fmaf(w.x, gy, gx * w.y)), gq, acc[j]);
    }
  }
#pragma unroll
  for (int j = 0; j < FT; ++j) {
    int f = fbase + j;
    if (f < F) Ab[(size_t)f * F + g] = __float2bfloat16(acc[j]);
  }
}

// ---------------- K4: reduce y1 partials (+x), sum/sumsq ----------------
__global__ __launch_bounds__(256) void k_stats1(const float* __restrict__ x,
                                                const float* __restrict__ Y1P,
                                                float* __restrict__ y1,
                                                float* __restrict__ st) {
  float s = 0.f, sq = 0.f;
  for (int i = blockIdx.x * 256 + threadIdx.x; i < BF; i += gridDim.x * 256) {
    float v = x[i];
#pragma unroll
    for (int k = 0; k < SF; ++k) v += Y1P[(size_t)k * BF + i];
    y1[i] = v;
    s += v; sq += v * v;
  }
#pragma unroll
  for (int o = 32; o; o >>= 1) {
    s += __shfl_down(s, o, 64);
    sq += __shfl_down(sq, o, 64);
  }
  __shared__ float ls[4], lq[4];
  int wave = threadIdx.x >> 6, lane = threadIdx.x & 63;
  if (lane == 0) { ls[wave] = s; lq[wave] = sq; }
  __syncthreads();
  if (threadIdx.x == 0) {
    atomicAdd(&st[0], ls[0] + ls[1] + ls[2] + ls[3]);
    atomicAdd(&st[1], lq[0] + lq[1] + lq[2] + lq[3]);
  }
}

// ---------------- K5: h1 = softsign(k_c*y1+c_c) -> Ht[f][m], y2 init ----------
__global__ __launch_bounds__(256) void k_h1(const float* __restrict__ y1,
                                            const float* __restrict__ st,
                                            const float* __restrict__ W1,
                                            const float* __restrict__ g1,
                                            const float* __restrict__ be1,
                                            float* __restrict__ Ht,
                                            float* __restrict__ y2) {
  float mu = st[0] / (float)BF;
  float var = st[1] / (float)BF - mu * mu;
  float wa = W1[0], wb = W1[1];
  float k0 = wa * g1[0] / sqrtf(wa * wa * var + EPS);
  float k1 = wb * g1[1] / sqrtf(wb * wb * var + EPS);
  float c0 = -k0 * mu + be1[0];
  float c1 = -k1 * mu + be1[1];

  __shared__ float H[16][132];
  const int f0 = blockIdx.x * 16;
#pragma unroll
  for (int r = 0; r < 4; ++r) {
    int idx = threadIdx.x + r * 256;
    int b = idx >> 4, ff = idx & 15;
    int f = f0 + ff;
    float v = (f < F) ? y1[b * F + f] : 0.f;
    float h0 = fmaf(k0, v, c0); h0 = h0 / (1.f + fabsf(h0));
    float h1 = fmaf(k1, v, c1); h1 = h1 / (1.f + fabsf(h1));
    H[ff][2 * b] = h0;
    H[ff][2 * b + 1] = h1;
  }
  __syncthreads();
#pragma unroll
  for (int r = 0; r < 2; ++r) {
    int idx = threadIdx.x + r * 256;
    int ff = idx >> 5, c4 = (idx & 31) * 4;
    int f = f0 + ff;
    if (f < F) *(float4*)&Ht[f * 128 + c4] = *(const float4*)&H[ff][c4];
  }
#pragma unroll
  for (int r = 0; r < 8; ++r) {
    int idx = threadIdx.x + r * 256;
    int m = idx >> 4, ff = idx & 15;
    int f = f0 + ff;
    if (f < F) y2[m * F + f] = 64.f * H[ff][m];
  }
}

// ---------------- K6: gemm partials G2P[s][m][f] ----------------
struct Pref { ushort a[4]; float4 h[4]; };

__device__ __forceinline__ void loadRegs(const ushort* __restrict__ Ab,
                                         const float* __restrict__ Ht,
                                         int f0, int ffs, int g4s, int tid,
                                         int gc, Pref& p) {
  int f = min(f0 + ffs, F - 1);
#pragma unroll
  for (int k = 0; k < 4; ++k) {
    int g = min(gc + g4s + k, F - 1);
    p.a[k] = Ab[(size_t)f * F + g];
  }
#pragma unroll
  for (int r = 0; r < 4; ++r) {
    int idx = tid + 256 * r;
    int gi = idx >> 5, c4 = (idx & 31) << 2;
    int g = min(gc + gi, F - 1);
    p.h[r] = *(const float4*)&Ht[g * 128 + c4];
  }
}

__device__ __forceinline__ void storeLDS(float* __restrict__ Al, float* __restrict__ Hl,
                                         int f0, int ffs, int g4s, int tid,
                                         int gc, int ge, const Pref& p) {
  bool fv = (f0 + ffs) < F;
#pragma unroll
  for (int k = 0; k < 4; ++k) {
    int g = gc + g4s + k;
    float v = 0.f;
    if (fv && g < ge) {
      __hip_bfloat16 bb = *(const __hip_bfloat16*)&p.a[k];
      v = __bfloat162float(bb);
    }
    Al[(g4s + k) * 36 + ffs] = v;
  }
#pragma unroll
  for (int r = 0; r < 4; ++r) {
    int idx = tid + 256 * r;
    int gi = idx >> 5, c4 = (idx & 31) << 2;
    float4 h = p.h[r];
    if (gc + gi >= ge) h = make_float4(0.f, 0.f, 0.f, 0.f);
    *(float4*)&Hl[gi * 132 + c4] = h;
  }
}

__global__ __launch_bounds__(256) void k_gemm(const ushort* __restrict__ Ab,
                                              const float* __restrict__ Ht,
                                              float* __restrict__ G2P) {
  __shared__ __align__(16) float Al[2][32 * 36];
  __shared__ __align__(16) float Hl[2][32 * 132];
  const int f0 = blockIdx.x * 32;
  const int gs = blockIdx.y * KCH;
  const int ge = min(gs + KCH, F);
  const int tid = threadIdx.x;
  const int ffs = tid >> 3;
  const int g4s = (tid & 7) * 4;
  const int fsub = (tid & 7) * 4;
  const int msub = (tid >> 3) * 4;
  float acc[4][4] = {};
  const int nch = (ge - gs + 31) >> 5;

  Pref p;
  loadRegs(Ab, Ht, f0, ffs, g4s, tid, gs, p);
  storeLDS(Al[0], Hl[0], f0, ffs, g4s, tid, gs, ge, p);
  __syncthreads();

  for (int c = 0; c < nch; ++c) {
    const int buf = c & 1;
    const bool more = (c + 1 < nch);
    if (more) loadRegs(Ab, Ht, f0, ffs, g4s, tid, gs + (c + 1) * 32, p);
    const float* Ab_ = Al[buf];
    const float* Hb_ = Hl[buf];
#pragma unroll 4
    for (int gi = 0; gi < 32; ++gi) {
      float4 a4 = *(const float4*)&Ab_[gi * 36 + fsub];
      float4 h4 = *(const float4*)&Hb_[gi * 132 + msub];
      float av[4] = {a4.x, a4.y, a4.z, a4.w};
      float hv[4] = {h4.x, h4.y, h4.z, h4.w};
#pragma unroll
      for (int i = 0; i < 4; ++i)
#pragma unroll
        for (int j = 0; j < 4; ++j)
          acc[i][j] = fmaf(av[i], hv[j], acc[i][j]);
    }
    if (more) storeLDS(Al[buf ^ 1], Hl[buf ^ 1], f0, ffs, g4s, tid, gs + (c + 1) * 32, ge, p);
    __syncthreads();
  }

  float* dst = G2P + (size_t)blockIdx.y * 128 * F;
#pragma unroll
  for (int i = 0; i < 4; ++i) {
    int f = f0 + fsub + i;
    if (f < F) {
#pragma unroll
      for (int j = 0; j < 4; ++j)
        dst[(msub + j) * F + f] = acc[i][j];
    }
  }
}

// ---------------- K7: reduce gemm partials into y2 + 5 moments ----------------
__global__ __launch_bounds__(256) void k_stats2(float* __restrict__ y2,
                                                const float* __restrict__ G2P,
                                                float* __restrict__ st) {
  float su = 0.f, sv = 0.f, suu = 0.f, svv = 0.f, suv = 0.f;
  for (int i = blockIdx.x * 256 + threadIdx.x; i < BF; i += gridDim.x * 256) {
    int b = i / F, f = i - b * F;
    int iu = (2 * b) * F + f, iv = iu + F;
    float u = y2[iu], v = y2[iv];
#pragma unroll
    for (int s = 0; s < SK; ++s) {
      u += G2P[(size_t)s * 128 * F + iu];
      v += G2P[(size_t)s * 128 * F + iv];
    }
    y2[iu] = u; y2[iv] = v;
    su += u; sv += v; suu += u * u; svv += v * v; suv += u * v;
  }
#pragma unroll
  for (int o = 32; o; o >>= 1) {
    su += __shfl_down(su, o, 64);
    sv += __shfl_down(sv, o, 64);
    suu += __shfl_down(suu, o, 64);
    svv += __shfl_down(svv, o, 64);
    suv += __shfl_down(suv, o, 64);
  }
  __shared__ float red[5][4];
  int wave = threadIdx.x >> 6, lane = threadIdx.x & 63;
  if (lane == 0) {
    red[0][wave] = su; red[1][wave] = sv; red[2][wave] = suu;
    red[3][wave] = svv; red[4][wave] = suv;
  }
  __syncthreads();
  if (threadIdx.x == 0) {
    atomicAdd(&st[2], red[0][0] + red[0][1] + red[0][2] + red[0][3]);
    atomicAdd(&st[3], red[1][0] + red[1][1] + red[1][2] + red[1][3]);
    atomicAdd(&st[4], red[2][0] + red[2][1] + red[2][2] + red[2][3]);
    atomicAdd(&st[5], red[3][0] + red[3][1] + red[3][2] + red[3][3]);
    atomicAdd(&st[6], red[4][0] + red[4][1] + red[4][2] + red[4][3]);
  }
}

// ---------------- K8: final classifier (BN2 consts inline) ----------------
__global__ __launch_bounds__(256) void k_out(const float* __restrict__ y2,
                                             const float* __restrict__ st,
                                             const float* __restrict__ W2,
                                             const float* __restrict__ b2,
                                             const float* __restrict__ g2,
                                             const float* __restrict__ be2,
                                             const float* __restrict__ Wc,
                                             const float* __restrict__ bc,
                                             float* __restrict__ out) {
  float n = (float)BF;
  float Eu = st[2] / n, Ev = st[3] / n;
  float Euu = st[4] / n, Evv = st[5] / n, Euv = st[6] / n;
  float cA[2], cB[2], cC[2];
#pragma unroll
  for (int o = 0; o < 2; ++o) {
    float w0 = W2[o * 2 + 0], w1 = W2[o * 2 + 1];
    float mean = w0 * Eu + w1 * Ev + b2[o];
    float Eh2 = w0 * w0 * Euu + 2.f * w0 * w1 * Euv + w1 * w1 * Evv +
                2.f * b2[o] * (w0 * Eu + w1 * Ev) + b2[o] * b2[o];
    float var = Eh2 - mean * mean;
    float inv = g2[o] / sqrtf(var + EPS);
    cA[o] = w0 * inv;
    cB[o] = w1 * inv;
    cC[o] = (b2[o] - mean) * inv + be2[o];
  }
  const int b = blockIdx.x;
  float acc[7] = {};
  for (int f = threadIdx.x; f < F; f += 256) {
    float u = y2[(2 * b) * F + f], v = y2[(2 * b + 1) * F + f];
    float h0 = fmaf(cA[0], u, fmaf(cB[0], v, cC[0]));
    h0 = h0 / (1.f + fabsf(h0));
    float h1 = fmaf(cA[1], u, fmaf(cB[1], v, cC[1]));
    h1 = h1 / (1.f + fabsf(h1));
#pragma unroll
    for (int o = 0; o < 7; ++o) acc[o] = fmaf(Wc[o * (2 * F) + f], h0, acc[o]);
#pragma unroll
    for (int o = 0; o < 7; ++o) acc[o] = fmaf(Wc[o * (2 * F) + F + f], h1, acc[o]);
  }
#pragma unroll
  for (int o = 0; o < 7; ++o) {
#pragma unroll
    for (int s = 32; s; s >>= 1) acc[o] += __shfl_down(acc[o], s, 64);
  }
  __shared__ float red[7][4];
  int wave = threadIdx.x >> 6, lane = threadIdx.x & 63;
  if (lane == 0) {
#pragma unroll
    for (int o = 0; o < 7; ++o) red[o][wave] = acc[o];
  }
  __syncthreads();
  if (threadIdx.x < 7) {
    int o = threadIdx.x;
    out[b * 7 + o] = red[o][0] + red[o][1] + red[o][2] + red[o][3] + bc[o];
  }
}

extern "C" void kernel_launch(void* const* d_in, const int* in_sizes, int n_in,
                              void* d_out, int out_size, void* d_ws, size_t ws_size,
                              hipStream_t stream) {
  const float* x    = (const float*)d_in[0];
  const float* nbr  = (const float*)d_in[1];
  const float* W1   = (const float*)d_in[3];
  const float* W2   = (const float*)d_in[5];
  const float* b2   = (const float*)d_in[6];
  const float* g1   = (const float*)d_in[7];
  const float* be1  = (const float*)d_in[8];
  const float* g2   = (const float*)d_in[9];
  const float* be2  = (const float*)d_in[10];
  const float* Wc   = (const float*)d_in[11];
  const float* bc   = (const float*)d_in[12];
  float* out = (float*)d_out;
  float* ws = (float*)d_ws;

  float* ys  = ws + O_YS;
  float* q   = ws + O_Q;
  float* DP  = ws + O_DP;    // reused as gemm partials G2P
  float* Y1P = ws + O_Y1P;
  float* y1  = ws + O_Y1;
  float* Ht  = ws + O_HT;
  float* y2  = ws + O_Y2;
  __hip_bfloat16* Ab = (__hip_bfloat16*)(ws + O_AB);
  float* st  = ws + O_ST;

  hipMemsetAsync(st, 0, 64 * sizeof(float), stream);

  k_D     <<<dim3(NB, SF), 256, 0, stream>>>(x, nbr, DP, ys);
  k_y1    <<<dim3(NB, SF), 256, 0, stream>>>(x, ys, DP, Y1P, q);
  k_A     <<<dim3(6, (F + FT - 1) / FT), 256, 0, stream>>>(x, ys, q, Ab);
  k_stats1<<<128, 256, 0, stream>>>(x, Y1P, y1, st);
  k_h1    <<<(F + 15) / 16, 256, 0, stream>>>(y1, st, W1, g1, be1, Ht, y2);
  k_gemm  <<<dim3((F + 31) / 32, SK), 256, 0, stream>>>((const ushort*)Ab, Ht, DP);
  k_stats2<<<128, 256, 0, stream>>>(y2, DP, st);
  k_out   <<<NB, 256, 0, stream>>>(y2, st, W2, b2, g2, be2, Wc, bc, out);
}